// Round 7
// baseline (220.984 us; speedup 1.0000x reference)
//
#include <hip/hip_runtime.h>
#include <hip/hip_cooperative_groups.h>
namespace cg = cooperative_groups;

typedef unsigned short u16;
typedef short bf16x8 __attribute__((ext_vector_type(8)));
typedef float f32x4 __attribute__((ext_vector_type(4)));
typedef u16 u16x4 __attribute__((ext_vector_type(4)));

__device__ __forceinline__ float b2f(u16 h) {
  unsigned u = ((unsigned)h) << 16;
  return __builtin_bit_cast(float, u);
}
// native RTNE f32->bf16; compiler pairs these into v_cvt_pk_bf16_f32
__device__ __forceinline__ u16 f2b(float f) {
  return __builtin_bit_cast(u16, (__bf16)f);
}
__device__ __forceinline__ void gld_lds16(const void* g, void* l) {
  __builtin_amdgcn_global_load_lds(
      (__attribute__((address_space(1))) void*)(g),
      (__attribute__((address_space(3))) void*)(l), 16, 0, 0);
}

// ---------------------------------------------------------------------------
// SINGLE cooperative kernel. 256 blocks x 512 thr, 1 block/CU (LDS 148 KB).
// Phase A: blocks 0-127 compute flat (16 nodes each): x cols -> LDS transpose
//   -> 3-layer MFMA chain with DIRECT fp32 pre_w reads (no staging kernel).
//   All blocks cvt W1/W2 frags direct from fp32 post_w into regs.
// grid.sync()  (device-scope fence -> flat visible across XCDs)
// Phase B: v6 main (parity-staggered symmetric pipeline), unchanged logic.
// Rationale: R1-R6 showed non-main time constant at ~75 us (3 dispatches,
// 2 serialization boundaries, xt + staged-weight round-trips) vs main 42 us.
// ---------------------------------------------------------------------------
#define NT 8  // tiles per block
__global__ __launch_bounds__(512, 2) void dense_edge_all(
    const float* __restrict__ x, const int* __restrict__ pidx,
    const int* __restrict__ cidx, const float* __restrict__ pre_w,
    const float* __restrict__ pre_b, const float* __restrict__ post_w,
    const float* __restrict__ post_b, const float* __restrict__ post_out_w,
    const float* __restrict__ post_out_b, u16* flat,
    float* __restrict__ out) {
  __shared__ __align__(16) u16 xxbuf[2][16384];    // B: [tile&1][cc][n][8]; A: fp32 tile
  __shared__ __align__(16) u16 t1buf[2][16384];    // B: t1 dbuf; A: feat ping-pong
  __shared__ __align__(16) u16 pstage[2048];
  __shared__ __align__(16) u16 qstage[2][2048];
  __shared__ float pbuf[2][8][2][64];

  const int t = threadIdx.x;
  const int wv = t >> 6;
  const int ln = t & 63;
  const int q4 = ln >> 4, r15 = ln & 15;
  const int blk = blockIdx.x;

  // ======================= PHASE A =======================
  if (blk < 128) {
    const int nb = blk * 16;
    const int bA = nb >> 10, hw0 = nb & 1023;
    float* tile = (float*)&xxbuf[0][0];   // [16][260] fp32, 16.6 KB
    u16* feat0 = &t1buf[0][0];            // [32 s8][16 n][8] bf16, 8 KB
    u16* feat1 = &t1buf[0][4096];
    // load x columns (c-major strided) into hw-major fp32 tile
    {
      const int c = t >> 1, half = t & 1;
      const float* src = x + (bA * 256 + c) * 1024 + hw0 + half * 8;
      f32x4 v0 = *(const f32x4*)src;
      f32x4 v1 = *(const f32x4*)(src + 4);
#pragma unroll
      for (int e = 0; e < 4; e++) {
        tile[(half * 8 + e) * 260 + c] = v0[e];
        tile[(half * 8 + 4 + e) * 260 + c] = v1[e];
      }
    }
    __syncthreads();
    // build feat0 bf16 [s8][n][8]
    {
      const float* p = tile + (t & 15) * 260 + (t >> 4) * 8;
      f32x4 a = *(const f32x4*)p, c4 = *(const f32x4*)(p + 4);
      bf16x8 o8;
#pragma unroll
      for (int k = 0; k < 4; k++) {
        o8[k] = (short)f2b(a[k]);
        o8[4 + k] = (short)f2b(c4[k]);
      }
      *(bf16x8*)(feat0 + t * 8) = o8;
    }
    __syncthreads();
    // 3-layer chain; 8 waves x 32 o-rows (2 mt); weights direct fp32
#pragma unroll 1
    for (int l = 0; l < 3; l++) {
      const float* wl = pre_w + l * 65536;
      bf16x8 wreg[2][8];
#pragma unroll
      for (int s = 0; s < 8; s++)
#pragma unroll
        for (int mt = 0; mt < 2; mt++) {
          const float* p = wl + (wv * 32 + mt * 16 + r15) * 256 + (s * 4 + q4) * 8;
          f32x4 a = *(const f32x4*)p, c4 = *(const f32x4*)(p + 4);
          bf16x8 o8;
#pragma unroll
          for (int k = 0; k < 4; k++) {
            o8[k] = (short)f2b(a[k]);
            o8[4 + k] = (short)f2b(c4[k]);
          }
          wreg[mt][s] = o8;
        }
      const u16* fin = (l & 1) ? feat1 : feat0;
      u16* fout = (l & 1) ? feat0 : feat1;
      f32x4 acc[2];
      acc[0] = {0.f, 0.f, 0.f, 0.f};
      acc[1] = {0.f, 0.f, 0.f, 0.f};
#pragma unroll
      for (int s = 0; s < 8; s++) {
        bf16x8 bv = *(const bf16x8*)(fin + ((s * 4 + q4) * 16 + r15) * 8);
#pragma unroll
        for (int mt = 0; mt < 2; mt++)
          acc[mt] = __builtin_amdgcn_mfma_f32_16x16x32_bf16(wreg[mt][s], bv, acc[mt], 0, 0, 0);
      }
      if (l < 2) {
#pragma unroll
        for (int mt = 0; mt < 2; mt++) {
          const int o = wv * 32 + mt * 16 + q4 * 4;
          f32x4 bb = *(const f32x4*)(pre_b + l * 256 + o);
          u16x4 pk;
#pragma unroll
          for (int r = 0; r < 4; r++) {
            float v = fmaxf(acc[mt][r] + bb[r], 0.f);
            pk[r] = f2b(v);
          }
          *(u16x4*)(fout + ((o >> 3) * 16 + r15) * 8 + (o & 7)) = pk;
        }
        __syncthreads();
      } else {
#pragma unroll
        for (int mt = 0; mt < 2; mt++) {
          const int o = wv * 32 + mt * 16 + q4 * 4;
          f32x4 bb = *(const f32x4*)(pre_b + 512 + o);
          u16x4 pk;
#pragma unroll
          for (int r = 0; r < 4; r++) pk[r] = f2b(acc[mt][r] + bb[r]);  // no relu
          *(u16x4*)(flat + (nb + r15) * 256 + o) = pk;
        }
      }
    }
    __threadfence();  // flat release (grid.sync also fences; belt+braces)
  }

  // all blocks: W1/W2 fragments direct from fp32 post_w
  bf16x8 w1f[2][8], w2f[2][8];
#pragma unroll
  for (int s = 0; s < 8; s++)
#pragma unroll
    for (int mt = 0; mt < 2; mt++) {
      const int o = wv * 32 + mt * 16 + r15, c0 = (s * 4 + q4) * 8;
      const float* p1 = post_w + o * 256 + c0;
      const float* p2 = post_w + 65536 + o * 256 + c0;
      f32x4 a1 = *(const f32x4*)p1, d1 = *(const f32x4*)(p1 + 4);
      f32x4 a2 = *(const f32x4*)p2, d2 = *(const f32x4*)(p2 + 4);
      bf16x8 o1, o2;
#pragma unroll
      for (int k = 0; k < 4; k++) {
        o1[k] = (short)f2b(a1[k]);
        o1[4 + k] = (short)f2b(d1[k]);
        o2[k] = (short)f2b(a2[k]);
        o2[4 + k] = (short)f2b(d2[k]);
      }
      w1f[mt][s] = o1;
      w2f[mt][s] = o2;
    }

  cg::this_grid().sync();

  // ======================= PHASE B (v6 main) =======================
  const float* b1 = post_b;
  const float* b2 = post_b + 256;
  const float* w3 = post_out_w;
  const float* b3 = post_out_b;

  const int tile0 = blk * NT;
  const int b = tile0 >> 10;
  const int pt = (tile0 >> 5) & 31;
  const int qt0 = tile0 & 31;
  const int p0 = pt * 8;

  // initial staging: waves 0-3 -> pstage, waves 4-7 -> qstage[0]
  const int slot4 = (wv & 3) * 64 + ln;
  const int srow = slot4 & 7, scc = slot4 >> 3;
  if (wv < 4) {
    const int pn = pidx[b * 256 + p0 + srow];
    gld_lds16(flat + pn * 256 + scc * 8, &pstage[slot4 * 8]);
  } else {
    const int qn = cidx[b * 256 + qt0 * 8 + srow];
    gld_lds16(flat + qn * 256 + scc * 8, &qstage[0][slot4 * 8]);
  }
  // preload q indices: tile 1 (prologue gld) and tile 2 (phase-0 gld)
  int qn_pro = 0, qn_cur = 0;
  if (wv >= 4) {
    qn_pro = cidx[b * 256 + (qt0 + 1) * 8 + srow];
    qn_cur = cidx[b * 256 + (qt0 + 2) * 8 + srow];
  }
  __syncthreads();

  const int prow = ln >> 3, qrow = ln & 7;

  // p-rows constant across tiles: hoist to registers
  bf16x8 pa[4];
#pragma unroll
  for (int i = 0; i < 4; i++)
    pa[i] = *(const bf16x8*)(&pstage[((wv * 4 + i) * 8 + prow) * 8]);

  auto do_xx = [&](int jx) {
    const u16* qs = qstage[jx & 1];
    u16* xb = xxbuf[jx & 1];
#pragma unroll
    for (int i = 0; i < 4; i++) {
      const int cc = wv * 4 + i;
      bf16x8 av = pa[i];
      bf16x8 bv = *(const bf16x8*)(&qs[(cc * 8 + qrow) * 8]);
      bf16x8 ov;
#pragma unroll
      for (int jj = 0; jj < 8; jj++) {
        float d = b2f((u16)av[jj]) - b2f((u16)bv[jj]);
        ov[jj] = (short)f2b(d * d);
      }
      *(bf16x8*)(&xb[(cc * 64 + ln) * 8]) = ov;
    }
  };

  auto do_g1 = [&](int jg) {
    const u16* xb = xxbuf[jg & 1];
    f32x4 acc[2][4];
    {
      f32x4 zero = {0.f, 0.f, 0.f, 0.f};
#pragma unroll
      for (int mt = 0; mt < 2; mt++)
#pragma unroll
        for (int nt = 0; nt < 4; nt++) acc[mt][nt] = zero;
    }
    __builtin_amdgcn_s_setprio(1);
#pragma unroll
    for (int s = 0; s < 8; s++) {
      bf16x8 bfr[4];
#pragma unroll
      for (int nt = 0; nt < 4; nt++)
        bfr[nt] = *(const bf16x8*)(xb + ((s * 4 + q4) * 64 + nt * 16 + r15) * 8);
#pragma unroll
      for (int mt = 0; mt < 2; mt++)
#pragma unroll
        for (int nt = 0; nt < 4; nt++)
          acc[mt][nt] = __builtin_amdgcn_mfma_f32_16x16x32_bf16(w1f[mt][s], bfr[nt], acc[mt][nt], 0, 0, 0);
    }
    __builtin_amdgcn_s_setprio(0);
#pragma unroll
    for (int mt = 0; mt < 2; mt++) {
      const int o = wv * 32 + mt * 16 + q4 * 4;
      f32x4 bb = *(const f32x4*)(b1 + o);
#pragma unroll
      for (int nt = 0; nt < 4; nt++) {
        const int nn = nt * 16 + r15;
        u16x4 pk;
#pragma unroll
        for (int r = 0; r < 4; r++) {
          float v = fmaxf(acc[mt][nt][r] + bb[r], 0.f);
          pk[r] = f2b(v);
        }
        *(u16x4*)(&t1buf[jg & 1][((o >> 3) * 64 + nn) * 8 + (o & 7)]) = pk;
      }
    }
  };

  auto do_g2 = [&](int jg) {
    const u16* tb = t1buf[jg & 1];
    f32x4 acc[2][4];
    {
      f32x4 zero = {0.f, 0.f, 0.f, 0.f};
#pragma unroll
      for (int mt = 0; mt < 2; mt++)
#pragma unroll
        for (int nt = 0; nt < 4; nt++) acc[mt][nt] = zero;
    }
    __builtin_amdgcn_s_setprio(1);
#pragma unroll
    for (int s = 0; s < 8; s++) {
      bf16x8 bfr[4];
#pragma unroll
      for (int nt = 0; nt < 4; nt++)
        bfr[nt] = *(const bf16x8*)(tb + ((s * 4 + q4) * 64 + nt * 16 + r15) * 8);
#pragma unroll
      for (int mt = 0; mt < 2; mt++)
#pragma unroll
        for (int nt = 0; nt < 4; nt++)
          acc[mt][nt] = __builtin_amdgcn_mfma_f32_16x16x32_bf16(w2f[mt][s], bfr[nt], acc[mt][nt], 0, 0, 0);
    }
    __builtin_amdgcn_s_setprio(0);
    float part[2][4] = {{0.f, 0.f, 0.f, 0.f}, {0.f, 0.f, 0.f, 0.f}};
#pragma unroll
    for (int mt = 0; mt < 2; mt++) {
      const int o = wv * 32 + mt * 16 + q4 * 4;
      f32x4 bb = *(const f32x4*)(b2 + o);
      f32x4 w3a = *(const f32x4*)(w3 + o);
      f32x4 w3b = *(const f32x4*)(w3 + 256 + o);
#pragma unroll
      for (int nt = 0; nt < 4; nt++) {
#pragma unroll
        for (int r = 0; r < 4; r++) {
          float v = fmaxf(acc[mt][nt][r] + bb[r], 0.f);
          part[0][nt] += v * w3a[r];
          part[1][nt] += v * w3b[r];
        }
      }
    }
#pragma unroll
    for (int o3 = 0; o3 < 2; o3++)
#pragma unroll
      for (int nt = 0; nt < 4; nt++) {
        part[o3][nt] += __shfl_xor(part[o3][nt], 16, 64);
        part[o3][nt] += __shfl_xor(part[o3][nt], 32, 64);
      }
    if (q4 == 0) {
#pragma unroll
      for (int o3 = 0; o3 < 2; o3++)
#pragma unroll
        for (int nt = 0; nt < 4; nt++)
          pbuf[jg & 1][wv][o3][nt * 16 + r15] = part[o3][nt];
    }
  };

  // prologue: XX(0); issue q-gather for tile 1
  do_xx(0);
  if (wv >= 4) gld_lds16(flat + qn_pro * 256 + scc * 8, &qstage[1][slot4 * 8]);
  __syncthreads();

#pragma unroll 1
  for (int j = 0; j <= NT; j++) {
    // ---- early: out(j-2) global store (drains under this phase's compute)
    if (j >= 2 && t < 128) {
      const int jo = j - 2;
      const int o3 = t >> 6;
      const int n = t & 63;
      float v = b3[o3];
#pragma unroll
      for (int k = 0; k < 8; k++) v += pbuf[jo & 1][k][o3][n];
      out[((b * 2 + o3) * 256 + p0 + (n >> 3)) * 256 + (qt0 + jo) * 8 + (n & 7)] = v;
    }
    // ---- early: q-gather for tile j+2 (address already in reg)
    if (j < NT - 2 && wv >= 4) {
      gld_lds16(flat + qn_cur * 256 + scc * 8, &qstage[j & 1][slot4 * 8]);
      if (j < NT - 3) qn_cur = cidx[b * 256 + (qt0 + j + 3) * 8 + srow];
    }
    // ---- parity-staggered work ----
    if (wv & 1) {
      if (j < NT - 1) do_xx(j + 1);
      if (j > 0) do_g2(j - 1);
      if (j < NT) do_g1(j);
    } else {
      if (j < NT) do_g1(j);
      if (j > 0) do_g2(j - 1);
      if (j < NT - 1) do_xx(j + 1);
    }
    __syncthreads();
  }

  // epilogue: out(NT-1)
  if (t < 128) {
    const int jo = NT - 1;
    const int o3 = t >> 6;
    const int n = t & 63;
    float v = b3[o3];
#pragma unroll
    for (int k = 0; k < 8; k++) v += pbuf[jo & 1][k][o3][n];
    out[((b * 2 + o3) * 256 + p0 + (n >> 3)) * 256 + (qt0 + jo) * 8 + (n & 7)] = v;
  }
}

// ---------------------------------------------------------------------------
extern "C" void kernel_launch(void* const* d_in, const int* in_sizes, int n_in,
                              void* d_out, int out_size, void* d_ws, size_t ws_size,
                              hipStream_t stream) {
  (void)in_sizes; (void)n_in; (void)out_size; (void)ws_size;
  const float* x          = (const float*)d_in[0];
  const int*   pidx       = (const int*)d_in[1];
  const int*   cidx       = (const int*)d_in[2];
  const float* pre_w      = (const float*)d_in[3];
  const float* pre_b      = (const float*)d_in[4];
  const float* post_w     = (const float*)d_in[5];
  const float* post_b     = (const float*)d_in[6];
  const float* post_out_w = (const float*)d_in[7];
  const float* post_out_b = (const float*)d_in[8];
  float* out = (float*)d_out;
  u16* flat = (u16*)d_ws;  // node features bf16 [2048][256]

  void* args[] = {(void*)&x,         (void*)&pidx,       (void*)&cidx,
                  (void*)&pre_w,     (void*)&pre_b,      (void*)&post_w,
                  (void*)&post_b,    (void*)&post_out_w, (void*)&post_out_b,
                  (void*)&flat,      (void*)&out};
  hipLaunchCooperativeKernel((const void*)dense_edge_all, dim3(256), dim3(512),
                             args, 0, stream);
}

// Round 8
// 129.754 us; speedup vs baseline: 1.7031x; 1.7031x over previous
//
#include <hip/hip_runtime.h>

typedef unsigned short u16;
typedef short bf16x8 __attribute__((ext_vector_type(8)));
typedef float f32x4 __attribute__((ext_vector_type(4)));
typedef u16 u16x4 __attribute__((ext_vector_type(4)));

__device__ __forceinline__ float b2f(u16 h) {
  unsigned u = ((unsigned)h) << 16;
  return __builtin_bit_cast(float, u);
}
// native RTNE f32->bf16; compiler pairs these into v_cvt_pk_bf16_f32
__device__ __forceinline__ u16 f2b(float f) {
  return __builtin_bit_cast(u16, (__bf16)f);
}
__device__ __forceinline__ void gld_lds16(const void* g, void* l) {
  __builtin_amdgcn_global_load_lds(
      (__attribute__((address_space(1))) void*)(g),
      (__attribute__((address_space(3))) void*)(l), 16, 0, 0);
}

// ---------------------------------------------------------------------------
// kernel1: fused flat-compute + W1/W2 staging (replaces prep+pre; no xt).
// blocks 0-127: 16 nodes each: x cols -> LDS fp32 transpose -> bf16 feat ->
//   3-layer MFMA chain with DIRECT fp32 pre_w reads (converted in-register).
//   (this body ran verified inside round-7's coop kernel)
// blocks 128-159: post_w fp32 -> bf16 STAGED layout [s8(32)][m(256)][8].
// ---------------------------------------------------------------------------
__global__ __launch_bounds__(512, 2) void dense_edge_flat(
    const float* __restrict__ x, const float* __restrict__ pre_w,
    const float* __restrict__ pre_b, const float* __restrict__ post_w,
    u16* __restrict__ wb, u16* __restrict__ flat) {
  const int t = threadIdx.x;
  const int blk = blockIdx.x;
  if (blk >= 128) {
    const int id = (blk - 128) * 512 + t;  // 16384 slots of 8 elems
    const int layer = id >> 13;            // 0..1
    const int sid = id & 8191;
    const int m = sid >> 5;
    const int s8 = sid & 31;
    const float* src = post_w + layer * 65536;
    u16* dst = wb + layer * 65536;
    f32x4 a = *(const f32x4*)(src + m * 256 + s8 * 8);
    f32x4 c = *(const f32x4*)(src + m * 256 + s8 * 8 + 4);
    bf16x8 o;
#pragma unroll
    for (int k = 0; k < 4; k++) {
      o[k] = (short)f2b(a[k]);
      o[4 + k] = (short)f2b(c[k]);
    }
    *(bf16x8*)(dst + (s8 * 256 + m) * 8) = o;
    return;
  }

  __shared__ __align__(16) float tile[16 * 260];  // 16.6 KB
  __shared__ __align__(16) u16 feat0[4096];       // [32 s8][16 n][8]
  __shared__ __align__(16) u16 feat1[4096];

  const int wv = t >> 6;
  const int ln = t & 63;
  const int q4 = ln >> 4, r15 = ln & 15;
  const int nb = blk * 16;
  const int bA = nb >> 10, hw0 = nb & 1023;

  // load x columns (c-major strided) into hw-major fp32 tile
  {
    const int c = t >> 1, half = t & 1;
    const float* src = x + (bA * 256 + c) * 1024 + hw0 + half * 8;
    f32x4 v0 = *(const f32x4*)src;
    f32x4 v1 = *(const f32x4*)(src + 4);
#pragma unroll
    for (int e = 0; e < 4; e++) {
      tile[(half * 8 + e) * 260 + c] = v0[e];
      tile[(half * 8 + 4 + e) * 260 + c] = v1[e];
    }
  }
  __syncthreads();
  // build feat0 bf16 [s8][n][8]
  {
    const float* p = tile + (t & 15) * 260 + (t >> 4) * 8;
    f32x4 a = *(const f32x4*)p, c4 = *(const f32x4*)(p + 4);
    bf16x8 o8;
#pragma unroll
    for (int k = 0; k < 4; k++) {
      o8[k] = (short)f2b(a[k]);
      o8[4 + k] = (short)f2b(c4[k]);
    }
    *(bf16x8*)(feat0 + t * 8) = o8;
  }
  __syncthreads();
  // 3-layer chain; 8 waves x 32 o-rows (2 mt); weights direct fp32
#pragma unroll 1
  for (int l = 0; l < 3; l++) {
    const float* wl = pre_w + l * 65536;
    bf16x8 wreg[2][8];
#pragma unroll
    for (int s = 0; s < 8; s++)
#pragma unroll
      for (int mt = 0; mt < 2; mt++) {
        const float* p = wl + (wv * 32 + mt * 16 + r15) * 256 + (s * 4 + q4) * 8;
        f32x4 a = *(const f32x4*)p, c4 = *(const f32x4*)(p + 4);
        bf16x8 o8;
#pragma unroll
        for (int k = 0; k < 4; k++) {
          o8[k] = (short)f2b(a[k]);
          o8[4 + k] = (short)f2b(c4[k]);
        }
        wreg[mt][s] = o8;
      }
    const u16* fin = (l & 1) ? feat1 : feat0;
    u16* fout = (l & 1) ? feat0 : feat1;
    f32x4 acc[2];
    acc[0] = {0.f, 0.f, 0.f, 0.f};
    acc[1] = {0.f, 0.f, 0.f, 0.f};
#pragma unroll
    for (int s = 0; s < 8; s++) {
      bf16x8 bv = *(const bf16x8*)(fin + ((s * 4 + q4) * 16 + r15) * 8);
#pragma unroll
      for (int mt = 0; mt < 2; mt++)
        acc[mt] = __builtin_amdgcn_mfma_f32_16x16x32_bf16(wreg[mt][s], bv, acc[mt], 0, 0, 0);
    }
    if (l < 2) {
#pragma unroll
      for (int mt = 0; mt < 2; mt++) {
        const int o = wv * 32 + mt * 16 + q4 * 4;
        f32x4 bb = *(const f32x4*)(pre_b + l * 256 + o);
        u16x4 pk;
#pragma unroll
        for (int r = 0; r < 4; r++) {
          float v = fmaxf(acc[mt][r] + bb[r], 0.f);
          pk[r] = f2b(v);
        }
        *(u16x4*)(fout + ((o >> 3) * 16 + r15) * 8 + (o & 7)) = pk;
      }
      __syncthreads();
    } else {
#pragma unroll
      for (int mt = 0; mt < 2; mt++) {
        const int o = wv * 32 + mt * 16 + q4 * 4;
        f32x4 bb = *(const f32x4*)(pre_b + 512 + o);
        u16x4 pk;
#pragma unroll
        for (int r = 0; r < 4; r++) pk[r] = f2b(acc[mt][r] + bb[r]);  // no relu
        *(u16x4*)(flat + (nb + r15) * 256 + o) = pk;
      }
    }
  }
}

// ---------------------------------------------------------------------------
// main v6 (unchanged, verified 42.4 us): symmetric pipeline + parity stagger.
// ---------------------------------------------------------------------------
#define NT 8  // tiles per block
__global__ __launch_bounds__(512, 2) void dense_edge_main(
    const u16* __restrict__ flat, const int* __restrict__ pidx,
    const int* __restrict__ cidx, const u16* __restrict__ w1s,
    const u16* __restrict__ w2s, const float* __restrict__ b1,
    const float* __restrict__ b2, const float* __restrict__ w3,
    const float* __restrict__ b3, float* __restrict__ out) {
  __shared__ u16 xxbuf[2][16384];    // [tile&1][cc(32)][n(64)][8]
  __shared__ u16 t1buf[2][16384];    // same layout
  __shared__ u16 pstage[2048];       // p-rows [cc(32)][row(8)][8]
  __shared__ u16 qstage[2][2048];    // q-rows, double-buffered by tile parity
  __shared__ float pbuf[2][8][2][64];// [tile&1][wave][o3][edge]

  const int t = threadIdx.x;
  const int wv = t >> 6;
  const int ln = t & 63;
  const int q4 = ln >> 4, r15 = ln & 15;
  const int blk = blockIdx.x;
  const int tile0 = blk * NT;
  const int b = tile0 >> 10;
  const int pt = (tile0 >> 5) & 31;
  const int qt0 = tile0 & 31;
  const int p0 = pt * 8;

  // both weight slices: 32 rows each of W1 and W2 (staged layout, 256B segs)
  bf16x8 w1f[2][8], w2f[2][8];
#pragma unroll
  for (int s = 0; s < 8; s++)
#pragma unroll
    for (int mt = 0; mt < 2; mt++) {
      const int off = ((s * 4 + q4) * 256 + wv * 32 + mt * 16 + r15) * 8;
      w1f[mt][s] = *(const bf16x8*)(w1s + off);
      w2f[mt][s] = *(const bf16x8*)(w2s + off);
    }

  // initial staging: waves 0-3 -> pstage, waves 4-7 -> qstage[0]
  const int slot4 = (wv & 3) * 64 + ln;
  const int srow = slot4 & 7, scc = slot4 >> 3;
  if (wv < 4) {
    const int pn = pidx[b * 256 + p0 + srow];
    gld_lds16(flat + pn * 256 + scc * 8, &pstage[slot4 * 8]);
  } else {
    const int qn = cidx[b * 256 + qt0 * 8 + srow];
    gld_lds16(flat + qn * 256 + scc * 8, &qstage[0][slot4 * 8]);
  }
  // preload q indices: tile 1 (prologue gld) and tile 2 (phase-0 gld)
  int qn_pro = 0, qn_cur = 0;
  if (wv >= 4) {
    qn_pro = cidx[b * 256 + (qt0 + 1) * 8 + srow];
    qn_cur = cidx[b * 256 + (qt0 + 2) * 8 + srow];
  }
  __syncthreads();

  const int prow = ln >> 3, qrow = ln & 7;

  // p-rows constant across tiles: hoist to registers (frees LDS path in XX)
  bf16x8 pa[4];
#pragma unroll
  for (int i = 0; i < 4; i++)
    pa[i] = *(const bf16x8*)(&pstage[((wv * 4 + i) * 8 + prow) * 8]);

  // ---- work items as lambdas (inlined twice for parity stagger) ----
  auto do_xx = [&](int jx) {
    const u16* qs = qstage[jx & 1];
    u16* xb = xxbuf[jx & 1];
#pragma unroll
    for (int i = 0; i < 4; i++) {
      const int cc = wv * 4 + i;
      bf16x8 av = pa[i];
      bf16x8 bv = *(const bf16x8*)(&qs[(cc * 8 + qrow) * 8]);
      bf16x8 ov;
#pragma unroll
      for (int jj = 0; jj < 8; jj++) {
        float d = b2f((u16)av[jj]) - b2f((u16)bv[jj]);
        ov[jj] = (short)f2b(d * d);
      }
      *(bf16x8*)(&xb[(cc * 64 + ln) * 8]) = ov;
    }
  };

  auto do_g1 = [&](int jg) {
    const u16* xb = xxbuf[jg & 1];
    f32x4 acc[2][4];
    {
      f32x4 zero = {0.f, 0.f, 0.f, 0.f};
#pragma unroll
      for (int mt = 0; mt < 2; mt++)
#pragma unroll
        for (int nt = 0; nt < 4; nt++) acc[mt][nt] = zero;
    }
    __builtin_amdgcn_s_setprio(1);
#pragma unroll
    for (int s = 0; s < 8; s++) {
      bf16x8 bfr[4];
#pragma unroll
      for (int nt = 0; nt < 4; nt++)
        bfr[nt] = *(const bf16x8*)(xb + ((s * 4 + q4) * 64 + nt * 16 + r15) * 8);
#pragma unroll
      for (int mt = 0; mt < 2; mt++)
#pragma unroll
        for (int nt = 0; nt < 4; nt++)
          acc[mt][nt] = __builtin_amdgcn_mfma_f32_16x16x32_bf16(w1f[mt][s], bfr[nt], acc[mt][nt], 0, 0, 0);
    }
    __builtin_amdgcn_s_setprio(0);
#pragma unroll
    for (int mt = 0; mt < 2; mt++) {
      const int o = wv * 32 + mt * 16 + q4 * 4;
      f32x4 bb = *(const f32x4*)(b1 + o);
#pragma unroll
      for (int nt = 0; nt < 4; nt++) {
        const int nn = nt * 16 + r15;
        u16x4 pk;
#pragma unroll
        for (int r = 0; r < 4; r++) {
          float v = fmaxf(acc[mt][nt][r] + bb[r], 0.f);
          pk[r] = f2b(v);
        }
        *(u16x4*)(&t1buf[jg & 1][((o >> 3) * 64 + nn) * 8 + (o & 7)]) = pk;
      }
    }
  };

  auto do_g2 = [&](int jg) {
    const u16* tb = t1buf[jg & 1];
    f32x4 acc[2][4];
    {
      f32x4 zero = {0.f, 0.f, 0.f, 0.f};
#pragma unroll
      for (int mt = 0; mt < 2; mt++)
#pragma unroll
        for (int nt = 0; nt < 4; nt++) acc[mt][nt] = zero;
    }
    __builtin_amdgcn_s_setprio(1);
#pragma unroll
    for (int s = 0; s < 8; s++) {
      bf16x8 bfr[4];
#pragma unroll
      for (int nt = 0; nt < 4; nt++)
        bfr[nt] = *(const bf16x8*)(tb + ((s * 4 + q4) * 64 + nt * 16 + r15) * 8);
#pragma unroll
      for (int mt = 0; mt < 2; mt++)
#pragma unroll
        for (int nt = 0; nt < 4; nt++)
          acc[mt][nt] = __builtin_amdgcn_mfma_f32_16x16x32_bf16(w2f[mt][s], bfr[nt], acc[mt][nt], 0, 0, 0);
    }
    __builtin_amdgcn_s_setprio(0);
    float part[2][4] = {{0.f, 0.f, 0.f, 0.f}, {0.f, 0.f, 0.f, 0.f}};
#pragma unroll
    for (int mt = 0; mt < 2; mt++) {
      const int o = wv * 32 + mt * 16 + q4 * 4;
      f32x4 bb = *(const f32x4*)(b2 + o);
      f32x4 w3a = *(const f32x4*)(w3 + o);
      f32x4 w3b = *(const f32x4*)(w3 + 256 + o);
#pragma unroll
      for (int nt = 0; nt < 4; nt++) {
#pragma unroll
        for (int r = 0; r < 4; r++) {
          float v = fmaxf(acc[mt][nt][r] + bb[r], 0.f);
          part[0][nt] += v * w3a[r];
          part[1][nt] += v * w3b[r];
        }
      }
    }
#pragma unroll
    for (int o3 = 0; o3 < 2; o3++)
#pragma unroll
      for (int nt = 0; nt < 4; nt++) {
        part[o3][nt] += __shfl_xor(part[o3][nt], 16, 64);
        part[o3][nt] += __shfl_xor(part[o3][nt], 32, 64);
      }
    if (q4 == 0) {
#pragma unroll
      for (int o3 = 0; o3 < 2; o3++)
#pragma unroll
        for (int nt = 0; nt < 4; nt++)
          pbuf[jg & 1][wv][o3][nt * 16 + r15] = part[o3][nt];
    }
  };

  // prologue: XX(0); issue q-gather for tile 1
  do_xx(0);
  if (wv >= 4) gld_lds16(flat + qn_pro * 256 + scc * 8, &qstage[1][slot4 * 8]);
  __syncthreads();

#pragma unroll 1
  for (int j = 0; j <= NT; j++) {
    // ---- early: out(j-2) global store (drains under this phase's compute)
    if (j >= 2 && t < 128) {
      const int jo = j - 2;
      const int o3 = t >> 6;
      const int n = t & 63;
      float v = b3[o3];
#pragma unroll
      for (int k = 0; k < 8; k++) v += pbuf[jo & 1][k][o3][n];
      out[((b * 2 + o3) * 256 + p0 + (n >> 3)) * 256 + (qt0 + jo) * 8 + (n & 7)] = v;
    }
    // ---- early: q-gather for tile j+2 (address already in reg)
    if (j < NT - 2 && wv >= 4) {
      gld_lds16(flat + qn_cur * 256 + scc * 8, &qstage[j & 1][slot4 * 8]);
      if (j < NT - 3) qn_cur = cidx[b * 256 + (qt0 + j + 3) * 8 + srow];
    }
    // ---- parity-staggered work ----
    if (wv & 1) {
      if (j < NT - 1) do_xx(j + 1);
      if (j > 0) do_g2(j - 1);
      if (j < NT) do_g1(j);
    } else {
      if (j < NT) do_g1(j);
      if (j > 0) do_g2(j - 1);
      if (j < NT - 1) do_xx(j + 1);
    }
    __syncthreads();
  }

  // epilogue: out(NT-1)
  if (t < 128) {
    const int jo = NT - 1;
    const int o3 = t >> 6;
    const int n = t & 63;
    float v = b3[o3];
#pragma unroll
    for (int k = 0; k < 8; k++) v += pbuf[jo & 1][k][o3][n];
    out[((b * 2 + o3) * 256 + p0 + (n >> 3)) * 256 + (qt0 + jo) * 8 + (n & 7)] = v;
  }
}

// ---------------------------------------------------------------------------
extern "C" void kernel_launch(void* const* d_in, const int* in_sizes, int n_in,
                              void* d_out, int out_size, void* d_ws, size_t ws_size,
                              hipStream_t stream) {
  (void)in_sizes; (void)n_in; (void)out_size; (void)ws_size;
  const float* x          = (const float*)d_in[0];
  const int*   pidx       = (const int*)d_in[1];
  const int*   cidx       = (const int*)d_in[2];
  const float* pre_w      = (const float*)d_in[3];
  const float* pre_b      = (const float*)d_in[4];
  const float* post_w     = (const float*)d_in[5];
  const float* post_b     = (const float*)d_in[6];
  const float* post_out_w = (const float*)d_in[7];
  const float* post_out_b = (const float*)d_in[8];
  float* out = (float*)d_out;

  u16* ws   = (u16*)d_ws;
  u16* w1s  = ws;              // staged bf16 W1 [s8][m][8]
  u16* w2s  = ws + 65536;      // staged bf16 W2
  u16* flat = ws + 131072;     // node features bf16 [2048][256]

  dense_edge_flat<<<160, 512, 0, stream>>>(x, pre_w, pre_b, post_w, ws, flat);
  dense_edge_main<<<256, 512, 0, stream>>>(flat, pidx, cidx, w1s, w2s,
                                           post_b, post_b + 256,
                                           post_out_w, post_out_b, out);
}

// Round 9
// 119.560 us; speedup vs baseline: 1.8483x; 1.0853x over previous
//
#include <hip/hip_runtime.h>

typedef unsigned short u16;
typedef short bf16x8 __attribute__((ext_vector_type(8)));
typedef float f32x4 __attribute__((ext_vector_type(4)));
typedef u16 u16x4 __attribute__((ext_vector_type(4)));

__device__ __forceinline__ float b2f(u16 h) {
  unsigned u = ((unsigned)h) << 16;
  return __builtin_bit_cast(float, u);
}
// native RTNE f32->bf16; compiler pairs these into v_cvt_pk_bf16_f32
__device__ __forceinline__ u16 f2b(float f) {
  return __builtin_bit_cast(u16, (__bf16)f);
}
__device__ __forceinline__ void gld_lds16(const void* g, void* l) {
  __builtin_amdgcn_global_load_lds(
      (__attribute__((address_space(1))) void*)(g),
      (__attribute__((address_space(3))) void*)(l), 16, 0, 0);
}

// ---------------------------------------------------------------------------
// prep (unchanged from R6): blocks [0,160): fp32 weights -> bf16 STAGED
//   [layer][s8(32)][m(256)][8]; layers: 0,1 = post_w; 2,3,4 = pre_w
// blocks [160,416): x [2][256][1024] fp32 -> xt [2048][256] bf16 (transpose)
// ---------------------------------------------------------------------------
__global__ void dense_edge_prep(const float* __restrict__ x,
                                const float* __restrict__ pre_w,
                                const float* __restrict__ post_w,
                                u16* __restrict__ wb, u16* __restrict__ xt) {
  const int blk = blockIdx.x;
  const int t = threadIdx.x;
  if (blk < 160) {
    const int id = blk * 256 + t;      // 40960 slots of 8 elems
    const int layer = id >> 13;        // 0..4
    const int sid = id & 8191;
    const int m = sid >> 5;
    const int s8 = sid & 31;
    const float* src = (layer < 2) ? (post_w + layer * 65536)
                                   : (pre_w + (layer - 2) * 65536);
    u16* dst = wb + layer * 65536;
    f32x4 a = *(const f32x4*)(src + m * 256 + s8 * 8);
    f32x4 c = *(const f32x4*)(src + m * 256 + s8 * 8 + 4);
    bf16x8 o;
#pragma unroll
    for (int j = 0; j < 4; j++) o[j] = (short)f2b(a[j]);
#pragma unroll
    for (int j = 0; j < 4; j++) o[4 + j] = (short)f2b(c[j]);
    *(bf16x8*)(dst + (s8 * 256 + m) * 8) = o;
  } else {
    __shared__ float tile[32 * 65];
    const int xb = blk - 160;          // 2 b x 8 ctile x 16 hwtile = 256
    const int b = xb >> 7;
    const int ct = (xb >> 4) & 7;
    const int ht = xb & 15;
    const int c0 = ct * 32, hw0 = ht * 64;
#pragma unroll
    for (int rep = 0; rep < 8; rep++) {
      const int idx = rep * 256 + t;
      const int cl = idx >> 6, hl = idx & 63;
      tile[cl * 65 + hl] = x[(b * 256 + c0 + cl) * 1024 + hw0 + hl];
    }
    __syncthreads();
    const int hl = t >> 2, c8 = t & 3;
    bf16x8 o;
#pragma unroll
    for (int i = 0; i < 8; i++) o[i] = (short)f2b(tile[(c8 * 8 + i) * 65 + hl]);
    *(bf16x8*)(xt + (b * 1024 + hw0 + hl) * 256 + c0 + c8 * 8) = o;
  }
}

// ---------------------------------------------------------------------------
// pre v2: 256 blocks x 8 nodes (was 128 x 16) -> full GPU, half the serial
// chain per block. Dense feat layout [s8(32)][n(8)][8]; MFMA cols 8-15 read
// garbage (padded LDS) and are discarded by r15<8 store guards.
// ---------------------------------------------------------------------------
__global__ __launch_bounds__(256, 2) void dense_edge_pre(
    const u16* __restrict__ xt, const u16* __restrict__ wpre,
    const float* __restrict__ preb, u16* __restrict__ flat) {
  __shared__ u16 feat[2][2112];  // [32 s8][8 n][8] + 64 pad for col-overread
  const int t = threadIdx.x;
  const int wv = t >> 6, ln = t & 63;
  const int nb = blockIdx.x * 8;
  const int q4 = ln >> 4, r15 = ln & 15;

  // stage 8 nodes: 256 slots, lane-linear dest
  {
    const int s8 = t >> 3, nl = t & 7;
    gld_lds16(xt + (nb + nl) * 256 + s8 * 8, &feat[0][t * 8]);
  }
  __syncthreads();

#pragma unroll
  for (int l = 0; l < 3; l++) {
    const u16* wl = wpre + l * 65536;
    f32x4 acc[4];
    f32x4 zero = {0.f, 0.f, 0.f, 0.f};
#pragma unroll
    for (int mt = 0; mt < 4; mt++) acc[mt] = zero;
#pragma unroll
    for (int s = 0; s < 8; s++) {
      // lanes r15>=8 read junk (within padded LDS) -> garbage cols, discarded
      bf16x8 bv = *(const bf16x8*)(&feat[l & 1][((s * 4 + q4) * 8 + r15) * 8]);
#pragma unroll
      for (int mt = 0; mt < 4; mt++) {
        bf16x8 av = *(const bf16x8*)(wl + ((s * 4 + q4) * 256 + wv * 64 + mt * 16 + r15) * 8);
        acc[mt] = __builtin_amdgcn_mfma_f32_16x16x32_bf16(av, bv, acc[mt], 0, 0, 0);
      }
    }
    if (l < 2) {
#pragma unroll
      for (int mt = 0; mt < 4; mt++) {
        const int o = wv * 64 + mt * 16 + q4 * 4;
        f32x4 bb = *(const f32x4*)(preb + l * 256 + o);
        u16x4 pk;
#pragma unroll
        for (int r = 0; r < 4; r++) {
          float v = fmaxf(acc[mt][r] + bb[r], 0.f);
          pk[r] = f2b(v);
        }
        if (r15 < 8)
          *(u16x4*)(&feat[(l + 1) & 1][((o >> 3) * 8 + r15) * 8 + (o & 7)]) = pk;
      }
      __syncthreads();
    } else {
#pragma unroll
      for (int mt = 0; mt < 4; mt++) {
        const int o = wv * 64 + mt * 16 + q4 * 4;
        f32x4 bb = *(const f32x4*)(preb + 512 + o);
        u16x4 pk;
#pragma unroll
        for (int r = 0; r < 4; r++) pk[r] = f2b(acc[mt][r] + bb[r]);  // no relu
        if (r15 < 8) *(u16x4*)(flat + (nb + r15) * 256 + o) = pk;
      }
    }
  }
}

// ---------------------------------------------------------------------------
// main v7: symmetric pipeline, stagger FIXED to (wv & 4).
// v6 staggered on wv&1, but waves map to SIMDs round-robin (wv%4): SIMD0
// hosts waves {0,4} - SAME parity -> both waves ran the same phase order and
// the MFMA/VALU cross-coverage never happened. wv&4 puts one g1-first and
// one xx-first wave on EVERY SIMD.
// ---------------------------------------------------------------------------
#define NT 8  // tiles per block
__global__ __launch_bounds__(512, 2) void dense_edge_main(
    const u16* __restrict__ flat, const int* __restrict__ pidx,
    const int* __restrict__ cidx, const u16* __restrict__ w1s,
    const u16* __restrict__ w2s, const float* __restrict__ b1,
    const float* __restrict__ b2, const float* __restrict__ w3,
    const float* __restrict__ b3, float* __restrict__ out) {
  __shared__ u16 xxbuf[2][16384];    // [tile&1][cc(32)][n(64)][8]
  __shared__ u16 t1buf[2][16384];    // same layout
  __shared__ u16 pstage[2048];       // p-rows [cc(32)][row(8)][8]
  __shared__ u16 qstage[2][2048];    // q-rows, double-buffered by tile parity
  __shared__ float pbuf[2][8][2][64];// [tile&1][wave][o3][edge]

  const int t = threadIdx.x;
  const int wv = t >> 6;
  const int ln = t & 63;
  const int q4 = ln >> 4, r15 = ln & 15;
  const int blk = blockIdx.x;
  const int tile0 = blk * NT;
  const int b = tile0 >> 10;
  const int pt = (tile0 >> 5) & 31;
  const int qt0 = tile0 & 31;
  const int p0 = pt * 8;

  // both weight slices: 32 rows each of W1 and W2 (staged layout, 256B segs)
  bf16x8 w1f[2][8], w2f[2][8];
#pragma unroll
  for (int s = 0; s < 8; s++)
#pragma unroll
    for (int mt = 0; mt < 2; mt++) {
      const int off = ((s * 4 + q4) * 256 + wv * 32 + mt * 16 + r15) * 8;
      w1f[mt][s] = *(const bf16x8*)(w1s + off);
      w2f[mt][s] = *(const bf16x8*)(w2s + off);
    }

  // initial staging: waves 0-3 -> pstage, waves 4-7 -> qstage[0]
  const int slot4 = (wv & 3) * 64 + ln;
  const int srow = slot4 & 7, scc = slot4 >> 3;
  if (wv < 4) {
    const int pn = pidx[b * 256 + p0 + srow];
    gld_lds16(flat + pn * 256 + scc * 8, &pstage[slot4 * 8]);
  } else {
    const int qn = cidx[b * 256 + qt0 * 8 + srow];
    gld_lds16(flat + qn * 256 + scc * 8, &qstage[0][slot4 * 8]);
  }
  // preload q indices: tile 1 (prologue gld) and tile 2 (phase-0 gld)
  int qn_pro = 0, qn_cur = 0;
  if (wv >= 4) {
    qn_pro = cidx[b * 256 + (qt0 + 1) * 8 + srow];
    qn_cur = cidx[b * 256 + (qt0 + 2) * 8 + srow];
  }
  __syncthreads();

  const int prow = ln >> 3, qrow = ln & 7;

  // p-rows constant across tiles: hoist to registers (frees LDS path in XX)
  bf16x8 pa[4];
#pragma unroll
  for (int i = 0; i < 4; i++)
    pa[i] = *(const bf16x8*)(&pstage[((wv * 4 + i) * 8 + prow) * 8]);

  // ---- work items as lambdas (inlined twice for SIMD-level stagger) ----
  auto do_xx = [&](int jx) {
    const u16* qs = qstage[jx & 1];
    u16* xb = xxbuf[jx & 1];
#pragma unroll
    for (int i = 0; i < 4; i++) {
      const int cc = wv * 4 + i;
      bf16x8 av = pa[i];
      bf16x8 bv = *(const bf16x8*)(&qs[(cc * 8 + qrow) * 8]);
      bf16x8 ov;
#pragma unroll
      for (int jj = 0; jj < 8; jj++) {
        float d = b2f((u16)av[jj]) - b2f((u16)bv[jj]);
        ov[jj] = (short)f2b(d * d);
      }
      *(bf16x8*)(&xb[(cc * 64 + ln) * 8]) = ov;
    }
  };

  auto do_g1 = [&](int jg) {
    const u16* xb = xxbuf[jg & 1];
    f32x4 acc[2][4];
    {
      f32x4 zero = {0.f, 0.f, 0.f, 0.f};
#pragma unroll
      for (int mt = 0; mt < 2; mt++)
#pragma unroll
        for (int nt = 0; nt < 4; nt++) acc[mt][nt] = zero;
    }
    __builtin_amdgcn_s_setprio(1);
#pragma unroll
    for (int s = 0; s < 8; s++) {
      bf16x8 bfr[4];
#pragma unroll
      for (int nt = 0; nt < 4; nt++)
        bfr[nt] = *(const bf16x8*)(xb + ((s * 4 + q4) * 64 + nt * 16 + r15) * 8);
#pragma unroll
      for (int mt = 0; mt < 2; mt++)
#pragma unroll
        for (int nt = 0; nt < 4; nt++)
          acc[mt][nt] = __builtin_amdgcn_mfma_f32_16x16x32_bf16(w1f[mt][s], bfr[nt], acc[mt][nt], 0, 0, 0);
    }
    __builtin_amdgcn_s_setprio(0);
#pragma unroll
    for (int mt = 0; mt < 2; mt++) {
      const int o = wv * 32 + mt * 16 + q4 * 4;
      f32x4 bb = *(const f32x4*)(b1 + o);
#pragma unroll
      for (int nt = 0; nt < 4; nt++) {
        const int nn = nt * 16 + r15;
        u16x4 pk;
#pragma unroll
        for (int r = 0; r < 4; r++) {
          float v = fmaxf(acc[mt][nt][r] + bb[r], 0.f);
          pk[r] = f2b(v);
        }
        *(u16x4*)(&t1buf[jg & 1][((o >> 3) * 64 + nn) * 8 + (o & 7)]) = pk;
      }
    }
  };

  auto do_g2 = [&](int jg) {
    const u16* tb = t1buf[jg & 1];
    f32x4 acc[2][4];
    {
      f32x4 zero = {0.f, 0.f, 0.f, 0.f};
#pragma unroll
      for (int mt = 0; mt < 2; mt++)
#pragma unroll
        for (int nt = 0; nt < 4; nt++) acc[mt][nt] = zero;
    }
    __builtin_amdgcn_s_setprio(1);
#pragma unroll
    for (int s = 0; s < 8; s++) {
      bf16x8 bfr[4];
#pragma unroll
      for (int nt = 0; nt < 4; nt++)
        bfr[nt] = *(const bf16x8*)(tb + ((s * 4 + q4) * 64 + nt * 16 + r15) * 8);
#pragma unroll
      for (int mt = 0; mt < 2; mt++)
#pragma unroll
        for (int nt = 0; nt < 4; nt++)
          acc[mt][nt] = __builtin_amdgcn_mfma_f32_16x16x32_bf16(w2f[mt][s], bfr[nt], acc[mt][nt], 0, 0, 0);
    }
    __builtin_amdgcn_s_setprio(0);
    float part[2][4] = {{0.f, 0.f, 0.f, 0.f}, {0.f, 0.f, 0.f, 0.f}};
#pragma unroll
    for (int mt = 0; mt < 2; mt++) {
      const int o = wv * 32 + mt * 16 + q4 * 4;
      f32x4 bb = *(const f32x4*)(b2 + o);
      f32x4 w3a = *(const f32x4*)(w3 + o);
      f32x4 w3b = *(const f32x4*)(w3 + 256 + o);
#pragma unroll
      for (int nt = 0; nt < 4; nt++) {
#pragma unroll
        for (int r = 0; r < 4; r++) {
          float v = fmaxf(acc[mt][nt][r] + bb[r], 0.f);
          part[0][nt] += v * w3a[r];
          part[1][nt] += v * w3b[r];
        }
      }
    }
#pragma unroll
    for (int o3 = 0; o3 < 2; o3++)
#pragma unroll
      for (int nt = 0; nt < 4; nt++) {
        part[o3][nt] += __shfl_xor(part[o3][nt], 16, 64);
        part[o3][nt] += __shfl_xor(part[o3][nt], 32, 64);
      }
    if (q4 == 0) {
#pragma unroll
      for (int o3 = 0; o3 < 2; o3++)
#pragma unroll
        for (int nt = 0; nt < 4; nt++)
          pbuf[jg & 1][wv][o3][nt * 16 + r15] = part[o3][nt];
    }
  };

  // prologue: XX(0); issue q-gather for tile 1
  do_xx(0);
  if (wv >= 4) gld_lds16(flat + qn_pro * 256 + scc * 8, &qstage[1][slot4 * 8]);
  __syncthreads();

#pragma unroll 1
  for (int j = 0; j <= NT; j++) {
    // ---- early: out(j-2) global store (drains under this phase's compute)
    if (j >= 2 && t < 128) {
      const int jo = j - 2;
      const int o3 = t >> 6;
      const int n = t & 63;
      float v = b3[o3];
#pragma unroll
      for (int k = 0; k < 8; k++) v += pbuf[jo & 1][k][o3][n];
      out[((b * 2 + o3) * 256 + p0 + (n >> 3)) * 256 + (qt0 + jo) * 8 + (n & 7)] = v;
    }
    // ---- early: q-gather for tile j+2 (address already in reg)
    if (j < NT - 2 && wv >= 4) {
      gld_lds16(flat + qn_cur * 256 + scc * 8, &qstage[j & 1][slot4 * 8]);
      if (j < NT - 3) qn_cur = cidx[b * 256 + (qt0 + j + 3) * 8 + srow];
    }
    // ---- SIMD-staggered work: each SIMD hosts waves {w, w+4} -> one of
    // each ordering per SIMD (wv&4, NOT wv&1 which pairs same-order waves)
    if (wv & 4) {
      if (j < NT - 1) do_xx(j + 1);
      if (j > 0) do_g2(j - 1);
      if (j < NT) do_g1(j);
    } else {
      if (j < NT) do_g1(j);
      if (j > 0) do_g2(j - 1);
      if (j < NT - 1) do_xx(j + 1);
    }
    __syncthreads();
  }

  // epilogue: out(NT-1)
  if (t < 128) {
    const int jo = NT - 1;
    const int o3 = t >> 6;
    const int n = t & 63;
    float v = b3[o3];
#pragma unroll
    for (int k = 0; k < 8; k++) v += pbuf[jo & 1][k][o3][n];
    out[((b * 2 + o3) * 256 + p0 + (n >> 3)) * 256 + (qt0 + jo) * 8 + (n & 7)] = v;
  }
}

// ---------------------------------------------------------------------------
extern "C" void kernel_launch(void* const* d_in, const int* in_sizes, int n_in,
                              void* d_out, int out_size, void* d_ws, size_t ws_size,
                              hipStream_t stream) {
  (void)in_sizes; (void)n_in; (void)out_size; (void)ws_size;
  const float* x          = (const float*)d_in[0];
  const int*   pidx       = (const int*)d_in[1];
  const int*   cidx       = (const int*)d_in[2];
  const float* pre_w      = (const float*)d_in[3];
  const float* pre_b      = (const float*)d_in[4];
  const float* post_w     = (const float*)d_in[5];
  const float* post_b     = (const float*)d_in[6];
  const float* post_out_w = (const float*)d_in[7];
  const float* post_out_b = (const float*)d_in[8];
  float* out = (float*)d_out;

  u16* ws   = (u16*)d_ws;
  u16* wb   = ws;              // staged bf16 weights: w1,w2,pre0,pre1,pre2
  u16* w1s  = wb;
  u16* w2s  = wb + 65536;
  u16* wpre = wb + 131072;
  u16* xt   = ws + 327680;     // x_t bf16 [2048][256]
  u16* flat = ws + 851968;     // node features bf16 [2048][256]

  dense_edge_prep<<<416, 256, 0, stream>>>(x, pre_w, post_w, wb, xt);
  dense_edge_pre<<<256, 256, 0, stream>>>(xt, wpre, pre_b, flat);
  dense_edge_main<<<256, 512, 0, stream>>>(flat, pidx, cidx, w1s, w2s,
                                           post_b, post_b + 256,
                                           post_out_w, post_out_b, out);
}